// Round 18
// baseline (67.789 us; speedup 1.0000x reference)
//
#include <hip/hip_runtime.h>

// Greedy NMS, M=16384 pts, radius 2.0, torch PairwiseDistance eps=1e-6.
// Output INT32: mask[16384] as 0/1, then count[1].
//
// Round 18: move active-list construction out of the 1-block solve into the
// 2048-block wscan. wscan writes out[i]=1 for inactive points (75% of out),
// and emits packed 8B entries (k,c,r0,r1,r2) for active points via a device
// atomic (set-deterministic; order-independent fixpoint). The solve loads
// entries coalesced into registers and runs the PROVEN r14 batched-Jacobi
// sweep. cnt[] eliminated. bin25 zeroes the entry counter.

#define M_PTS    16384
#define RADIUS   2.0f
#define EPS_D    1e-6f
#define GRID_N   25        // 4 m cells over 100 m scene
#define NCELLS   (GRID_N * GRID_N * GRID_N)
#define CELL_CAP 12
#define K_NBR    12
#define CELLS_PB (GRID_N * GRID_N)        // 625 cells per bin-block
#define LIST_PB  (CELLS_PB * CELL_CAP)    // 7500 entries per bin-block
#define EPT      5
#define ACT_PAD  (EPT * 1024)             // 5120; E[active]~3932, ~21 sigma
#define SENT     M_PTS                    // always-0 sentinel byte index

// ws layout (bytes):
//   [0,       262144) float4 pts[16384]
//   [262144,  324644) int    cell_cnt[15625]
//   [327680,  327684) int    actn
//   [393216,  768216) ushort cell_list[15625*12]
//   [770048, 1163264) ushort nbr[16384*12]
//   [1179648, 1310720) uint2 act[16384]   (8B packed entries)

__device__ __forceinline__ int cell_of(float v) {
  int c = (int)(v * 0.25f);
  return c < 0 ? 0 : (c > GRID_N - 1 ? GRID_N - 1 : c);
}

__device__ __forceinline__ bool edge_test(float4 pi, float4 pj, int j, int i) {
  // j earlier in argsort(-score, stable) AND torch-dist <= radius (exact math)
  bool earlier = (pj.w > pi.w) || ((pj.w == pi.w) && (j < i));
  if (!earlier) return false;
  float ddx = __fadd_rn(__fsub_rn(pi.x, pj.x), EPS_D);
  float ddy = __fadd_rn(__fsub_rn(pi.y, pj.y), EPS_D);
  float ddz = __fadd_rn(__fsub_rn(pi.z, pj.z), EPS_D);
  float d2 = __fadd_rn(__fadd_rn(__fmul_rn(ddx, ddx), __fmul_rn(ddy, ddy)),
                       __fmul_rn(ddz, ddz));
  return !(__fsqrt_rn(d2) > RADIUS);
}

// ---- K1: 25 blocks; block b owns all cells with cx==b (unchanged r11). ----
__global__ __launch_bounds__(1024) void bin25(
    const float* __restrict__ nodes, const float* __restrict__ score,
    float4* __restrict__ pts, int* __restrict__ cell_cnt,
    unsigned short* __restrict__ cell_list, int* __restrict__ actn) {
  __shared__ int ccnt[CELLS_PB];              // 2.5 KB
  __shared__ unsigned short clist[LIST_PB];   // 15 KB
  const int tid = threadIdx.x;
  const int b   = blockIdx.x;
  if (b == 0 && tid == 0) *actn = 0;          // ordered before wscan by boundary
  if (tid < CELLS_PB) ccnt[tid] = 0;
  __syncthreads();

  for (int i = tid; i < M_PTS; i += 1024) {
    float x = nodes[3 * i + 0];
    if (cell_of(x) != b) continue;
    float y = nodes[3 * i + 1];
    float z = nodes[3 * i + 2];
    float s = score[i];
    pts[i] = make_float4(x, y, z, s);
    int lc = cell_of(y) * GRID_N + cell_of(z);
    int pos = atomicAdd(&ccnt[lc], 1);
    if (pos < CELL_CAP) clist[lc * CELL_CAP + pos] = (unsigned short)i;
  }
  __syncthreads();

  if (tid < CELLS_PB) {
    int v = ccnt[tid];
    cell_cnt[b * CELLS_PB + tid] = v > CELL_CAP ? CELL_CAP : v;
  }
  for (int e = tid; e < LIST_PB; e += 1024)
    cell_list[b * LIST_PB + e] = clist[e];
}

// ---- K2: 2 points/wave, one cell/lane; emits inactive outs + active entries ----
__global__ __launch_bounds__(256) void wscan(
    const float4* __restrict__ pts, const int* __restrict__ cell_cnt,
    const unsigned short* __restrict__ cell_list,
    unsigned short* __restrict__ nbr, uint2* __restrict__ actg,
    int* __restrict__ actn, int* __restrict__ out) {
  const int tid  = threadIdx.x;
  const int lane = tid & 63;
  const int d    = lane & 31;
  const int half = lane >> 5;
  const int gwave = (blockIdx.x * 256 + tid) >> 6;
  const int i = gwave * 2 + half;

  const float4 pi = pts[i];
  int n = 0, cid = 0, m = 0;
  int j0 = 0, j1 = 0, j2 = 0;     // this lane's first 3 edge ids
  if (d < 27) {
    int cx = cell_of(pi.x) + d / 9 - 1;
    int cy = cell_of(pi.y) + (d / 3) % 3 - 1;
    int cz = cell_of(pi.z) + d % 3 - 1;
    if (cx >= 0 && cx < GRID_N && cy >= 0 && cy < GRID_N &&
        cz >= 0 && cz < GRID_N) {
      cid = (cx * GRID_N + cy) * GRID_N + cz;
      m = cell_cnt[cid];
      for (int s = 0; s < m; ++s) {
        int j = cell_list[cid * CELL_CAP + s];
        if (edge_test(pi, pts[j], j, i)) {
          if (n == 0) j0 = j; else if (n == 1) j1 = j; else if (n == 2) j2 = j;
          ++n;
        }
      }
    }
  }
  // segmented inclusive scan over the 32-lane half -> packing offsets
  int x = n;
#pragma unroll
  for (int off = 1; off < 32; off <<= 1) {
    int y = __shfl_up(x, off, 32);
    if (d >= off) x += y;
  }
  int excl = x - n;
  int tot = __shfl(x, 31, 32);
  // write nbr row (needed by solve only for c>3 tail; cheap, keep proven path)
  if (n == 1) {
    if (excl < K_NBR) nbr[i * K_NBR + excl] = (unsigned short)j0;
  } else if (n > 1) {
    int pos = excl;
    for (int s = 0; s < m && pos < K_NBR; ++s) {
      int j = cell_list[cid * CELL_CAP + s];
      if (edge_test(pi, pts[j], j, i)) {
        nbr[i * K_NBR + pos] = (unsigned short)j;
        ++pos;
      }
    }
  }
  // gather row positions 0..2 across the half (delta = p - excl[src] <= 2)
  unsigned short rr0 = 0, rr1 = 0, rr2 = 0;
#pragma unroll
  for (int p = 0; p < 3; ++p) {
    bool pred = (excl <= p) && (p < excl + n);
    unsigned long long bal = __ballot(pred);
    unsigned bh = (unsigned)(bal >> (half * 32));
    int src = half * 32 + (bh ? (__ffs(bh) - 1) : 0);
    int sj0 = __shfl(j0, src, 64);
    int sj1 = __shfl(j1, src, 64);
    int sj2 = __shfl(j2, src, 64);
    int se  = __shfl(excl, src, 64);
    int dp = p - se;
    unsigned short rp = (unsigned short)(dp == 0 ? sj0 : dp == 1 ? sj1 : sj2);
    if (p == 0) rr0 = rp; else if (p == 1) rr1 = rp; else rr2 = rp;
  }
  if (d == 0) {
    if (tot == 0) {
      out[i] = 1;                 // inactive: kept forever, final
    } else {
      int c = tot > K_NBR ? K_NBR : tot;
      int pos = atomicAdd(actn, 1);   // device-scope; order nondeterministic
      unsigned e0 = (unsigned)i | ((unsigned)c << 14) | ((unsigned)rr0 << 18);
      unsigned e1 = (unsigned)rr1 | ((unsigned)rr2 << 16);
      actg[pos] = make_uint2(e0, e1);
    }
  }
}

// ---- K3: slim solve — entries straight to registers, r14 sweep body ----
__global__ __launch_bounds__(1024) void solve_pk(
    const uint2* __restrict__ actg, const int* __restrict__ actn,
    const unsigned short* __restrict__ nbr,
    int* __restrict__ out, int out_size) {
  __shared__ unsigned char mask[M_PTS + 4];  // +sentinel (index SENT == 0)
  __shared__ int total;

  const int tid = threadIdx.x;
  const int lane = tid & 63;
  if (tid == 0) total = 0;
  unsigned int* mask4 = (unsigned int*)mask;
  for (int w = tid; w < M_PTS / 4; w += 1024) mask4[w] = 0x01010101u;
  if (tid == 0) mask4[M_PTS / 4] = 0u;       // sentinel byte = 0

  const int na = *actn;
  const bool ok = (na <= ACT_PAD);

  // coalesced register staging of this thread's <=5 entries
  unsigned ae[EPT];
  unsigned short r0[EPT], r1[EPT], r2[EPT];
  int cur[EPT];
#pragma unroll
  for (int e = 0; e < EPT; ++e) {
    int idx = tid + e * 1024;
    uint2 ev = (ok && idx < na) ? actg[idx] : make_uint2(0u, 0u);
    int k = (int)(ev.x & 0x3FFFu);
    int c = (int)((ev.x >> 14) & 0xFu);
    ae[e] = (unsigned)k | ((unsigned)c << 16);
    r0[e] = (c > 0) ? (unsigned short)(ev.x >> 18)      : (unsigned short)SENT;
    r1[e] = (c > 1) ? (unsigned short)(ev.y & 0xFFFFu)  : (unsigned short)SENT;
    r2[e] = (c > 2) ? (unsigned short)(ev.y >> 16)      : (unsigned short)SENT;
    cur[e] = 1;
  }
  __syncthreads();

  if (ok) {
    for (int it = 0; it < 96; ++it) {
      // batched independent LDS byte reads (proven r14 body)
      int m0[EPT], m1[EPT], m2[EPT];
#pragma unroll
      for (int e = 0; e < EPT; ++e) m0[e] = (int)mask[r0[e]];
#pragma unroll
      for (int e = 0; e < EPT; ++e) m1[e] = (int)mask[r1[e]];
#pragma unroll
      for (int e = 0; e < EPT; ++e) m2[e] = (int)mask[r2[e]];
      int any = 0;
#pragma unroll
      for (int e = 0; e < EPT; ++e) {
        unsigned v = ae[e];
        int c = (int)(v >> 16);
        if (!c) continue;
        int kp = (m0[e] ^ 1) & (m1[e] ^ 1) & (m2[e] ^ 1);
        if (c > 3) {   // ~0.2% of actives: global tail
          int k = (int)(v & 0xFFFFu);
          const unsigned short* row = nbr + (size_t)k * K_NBR;
          for (int t = 3; t < c; ++t) kp &= (int)mask[row[t]] ^ 1;
        }
        if (kp != cur[e]) {
          cur[e] = kp;
          mask[v & 0xFFFFu] = (unsigned char)kp;   // single writer per entry
          any = 1;
        }
      }
      if (__syncthreads_count(any) == 0) break;
    }
    // output: only active entries (inactive written by wscan); count formula
    int ks = 0;
#pragma unroll
    for (int e = 0; e < EPT; ++e) {
      unsigned v = ae[e];
      if ((v >> 16) != 0u) {
        out[v & 0xFFFFu] = cur[e];
        ks += cur[e];
      }
    }
#pragma unroll
    for (int off = 32; off > 0; off >>= 1) ks += __shfl_down(ks, off, 64);
    if (lane == 0) atomicAdd(&total, ks);
    __syncthreads();
    if (tid == 0) out[out_size - 1] = (M_PTS - na) + total;
  } else {
    // overflow fallback (statistically never): sweep global entry array
    __shared__ int changed;
    for (int it = 0; it < 512; ++it) {
      if (tid == 0) changed = 0;
      __syncthreads();
      int any = 0;
      for (int idx = tid; idx < na; idx += 1024) {
        uint2 ev = actg[idx];
        int k = (int)(ev.x & 0x3FFFu);
        int c = (int)((ev.x >> 14) & 0xFu);
        int kp = (int)mask[(unsigned short)(ev.x >> 18)] ^ 1;
        if (c > 1) kp &= (int)mask[(unsigned short)(ev.y & 0xFFFFu)] ^ 1;
        if (c > 2) kp &= (int)mask[(unsigned short)(ev.y >> 16)] ^ 1;
        if (c > 3) {
          const unsigned short* row = nbr + (size_t)k * K_NBR;
          for (int t = 3; t < c; ++t) kp &= (int)mask[row[t]] ^ 1;
        }
        if (kp != (int)mask[k]) { mask[k] = (unsigned char)kp; any = 1; }
      }
      if (any) changed = 1;
      __syncthreads();
      if (!changed) break;
    }
    __syncthreads();
    int ks = 0;
    for (int idx = tid; idx < na; idx += 1024) {
      int k = (int)(actg[idx].x & 0x3FFFu);
      int mv = (int)mask[k];
      out[k] = mv;
      ks += mv;
    }
#pragma unroll
    for (int off = 32; off > 0; off >>= 1) ks += __shfl_down(ks, off, 64);
    if (lane == 0) atomicAdd(&total, ks);
    __syncthreads();
    if (tid == 0) out[out_size - 1] = (M_PTS - na) + total;
  }
}

extern "C" void kernel_launch(void* const* d_in, const int* in_sizes, int n_in,
                              void* d_out, int out_size, void* d_ws, size_t ws_size,
                              hipStream_t stream) {
  const float* nodes = (const float*)d_in[0];
  const float* score = (const float*)d_in[1];
  int* out = (int*)d_out;

  char* ws = (char*)d_ws;
  float4* pts = (float4*)ws;
  int* cell_cnt = (int*)(ws + 262144);
  int* actn = (int*)(ws + 327680);
  unsigned short* cell_list = (unsigned short*)(ws + 393216);
  unsigned short* nbr = (unsigned short*)(ws + 770048);
  uint2* actg = (uint2*)(ws + 1179648);

  bin25<<<GRID_N, 1024, 0, stream>>>(nodes, score, pts, cell_cnt, cell_list, actn);
  wscan<<<2048, 256, 0, stream>>>(pts, cell_cnt, cell_list, nbr, actg, actn, out);
  solve_pk<<<1, 1024, 0, stream>>>(actg, actn, nbr, out, out_size);
}

// Round 19
// 39.426 us; speedup vs baseline: 1.7194x; 1.7194x over previous
//
#include <hip/hip_runtime.h>

// Greedy NMS, M=16384 pts, radius 2.0, torch PairwiseDistance eps=1e-6.
// Output INT32: mask[16384] as 0/1, then count[1].
//
// Round 19: r14 champion (39.1us) + the benign half of r18:
//  - wscan writes out[i]=1 for inactive points (NO global atomic — r18's
//    46us regression was ~3.9K single-address device atomicAdds).
//  - solve epilogue writes only active outputs from registers; count =
//    (M - na) + sum(active). Drops the 16-step mask-read + 64KB out pass.
// Everything else byte-identical to r14.

#define M_PTS    16384
#define RADIUS   2.0f
#define EPS_D    1e-6f
#define GRID_N   25        // 4 m cells over 100 m scene
#define NCELLS   (GRID_N * GRID_N * GRID_N)
#define CELL_CAP 12
#define K_NBR    12
#define CELLS_PB (GRID_N * GRID_N)        // 625 cells per bin-block
#define LIST_PB  (CELLS_PB * CELL_CAP)    // 7500 entries per bin-block
#define EPT      5
#define ACT_PAD  (EPT * 1024)   // 5120; E[active]~3932, sigma~55
#define SENT     M_PTS          // index of the always-0 sentinel byte

// ws layout (bytes):
//   [0,       262144) float4 pts[16384]
//   [262144,  324644) int    cell_cnt[15625]
//   [327680,  393216) int    cnt[16384]
//   [393216,  768216) ushort cell_list[15625*12]
//   [770048, 1163264) ushort nbr[16384*12]

__device__ __forceinline__ int cell_of(float v) {
  int c = (int)(v * 0.25f);
  return c < 0 ? 0 : (c > GRID_N - 1 ? GRID_N - 1 : c);
}

__device__ __forceinline__ bool edge_test(float4 pi, float4 pj, int j, int i) {
  // j earlier in argsort(-score, stable) AND torch-dist <= radius (exact math)
  bool earlier = (pj.w > pi.w) || ((pj.w == pi.w) && (j < i));
  if (!earlier) return false;
  float ddx = __fadd_rn(__fsub_rn(pi.x, pj.x), EPS_D);
  float ddy = __fadd_rn(__fsub_rn(pi.y, pj.y), EPS_D);
  float ddz = __fadd_rn(__fsub_rn(pi.z, pj.z), EPS_D);
  float d2 = __fadd_rn(__fadd_rn(__fmul_rn(ddx, ddx), __fmul_rn(ddy, ddy)),
                       __fmul_rn(ddz, ddz));
  return !(__fsqrt_rn(d2) > RADIUS);
}

// ---- K1: 25 blocks; block b owns all cells with cx==b (unchanged r11). ----
__global__ __launch_bounds__(1024) void bin25(
    const float* __restrict__ nodes, const float* __restrict__ score,
    float4* __restrict__ pts, int* __restrict__ cell_cnt,
    unsigned short* __restrict__ cell_list) {
  __shared__ int ccnt[CELLS_PB];              // 2.5 KB
  __shared__ unsigned short clist[LIST_PB];   // 15 KB
  const int tid = threadIdx.x;
  const int b   = blockIdx.x;
  if (tid < CELLS_PB) ccnt[tid] = 0;
  __syncthreads();

  for (int i = tid; i < M_PTS; i += 1024) {
    float x = nodes[3 * i + 0];
    if (cell_of(x) != b) continue;
    float y = nodes[3 * i + 1];
    float z = nodes[3 * i + 2];
    float s = score[i];
    pts[i] = make_float4(x, y, z, s);
    int lc = cell_of(y) * GRID_N + cell_of(z);
    int pos = atomicAdd(&ccnt[lc], 1);
    if (pos < CELL_CAP) clist[lc * CELL_CAP + pos] = (unsigned short)i;
  }
  __syncthreads();

  if (tid < CELLS_PB) {
    int v = ccnt[tid];
    cell_cnt[b * CELLS_PB + tid] = v > CELL_CAP ? CELL_CAP : v;
  }
  for (int e = tid; e < LIST_PB; e += 1024)
    cell_list[b * LIST_PB + e] = clist[e];
}

// ---- K2: 2 points/wave, one cell/lane; + inactive-out direct write ----
__global__ __launch_bounds__(256) void wscan(
    const float4* __restrict__ pts, const int* __restrict__ cell_cnt,
    const unsigned short* __restrict__ cell_list,
    int* __restrict__ cnt, unsigned short* __restrict__ nbr,
    int* __restrict__ out) {
  const int tid  = threadIdx.x;
  const int lane = tid & 63;
  const int d    = lane & 31;
  const int half = lane >> 5;
  const int gwave = (blockIdx.x * 256 + tid) >> 6;
  const int i = gwave * 2 + half;

  const float4 pi = pts[i];
  int n = 0, cid = 0, m = 0, firstj = 0;
  if (d < 27) {
    int cx = cell_of(pi.x) + d / 9 - 1;
    int cy = cell_of(pi.y) + (d / 3) % 3 - 1;
    int cz = cell_of(pi.z) + d % 3 - 1;
    if (cx >= 0 && cx < GRID_N && cy >= 0 && cy < GRID_N &&
        cz >= 0 && cz < GRID_N) {
      cid = (cx * GRID_N + cy) * GRID_N + cz;
      m = cell_cnt[cid];
      for (int s = 0; s < m; ++s) {
        int j = cell_list[cid * CELL_CAP + s];
        if (edge_test(pi, pts[j], j, i)) { if (!n) firstj = j; ++n; }
      }
    }
  }
  int x = n;
#pragma unroll
  for (int off = 1; off < 32; off <<= 1) {
    int y = __shfl_up(x, off, 32);
    if (d >= off) x += y;
  }
  int excl = x - n;
  int tot = __shfl(x, 31, 32);
  if (n == 1) {
    if (excl < K_NBR) nbr[i * K_NBR + excl] = (unsigned short)firstj;
  } else if (n > 1) {
    int pos = excl;
    for (int s = 0; s < m && pos < K_NBR; ++s) {
      int j = cell_list[cid * CELL_CAP + s];
      if (edge_test(pi, pts[j], j, i)) {
        nbr[i * K_NBR + pos] = (unsigned short)j;
        ++pos;
      }
    }
  }
  if (d == 0) {
    cnt[i] = tot > K_NBR ? K_NBR : tot;
    if (tot == 0) out[i] = 1;   // inactive: kept forever, final value
  }
}

// ---- K3: r14 solve; epilogue writes only active outs + count formula ----
__global__ __launch_bounds__(1024) void solve_nb(
    const int* __restrict__ cnt, const unsigned short* __restrict__ nbr,
    int* __restrict__ out, int out_size) {
  __shared__ unsigned char mask[M_PTS + 4];  // +sentinel (index SENT == 0)
  __shared__ unsigned int act[ACT_PAD];      // 20 KB: k | (c<<16)
  __shared__ int act_n, total;

  const int tid = threadIdx.x;
  const int lane = tid & 63;
  if (tid == 0) { act_n = 0; total = 0; }
  unsigned int* mask4 = (unsigned int*)mask;
  for (int w = tid; w < M_PTS / 4; w += 1024) mask4[w] = 0x01010101u;
  if (tid == 0) mask4[M_PTS / 4] = 0u;       // sentinel byte = 0 (suppressed)
  for (int a = tid; a < ACT_PAD; a += 1024) act[a] = 0u;  // c=0 sentinels
  __syncthreads();

  // active-list build: ballot compaction, one atomic per wave per step
  for (int k = tid; k < M_PTS; k += 1024) {
    int c = cnt[k];
    if (c > K_NBR) c = K_NBR;
    unsigned long long b = __ballot(c > 0);
    int wcnt = __popcll(b);
    int wbase = 0;
    if (lane == 0 && wcnt) wbase = atomicAdd(&act_n, wcnt);
    wbase = __shfl(wbase, 0, 64);
    if (c > 0) {
      int pos = wbase + __popcll(b & ((1ull << lane) - 1ull));
      if (pos < ACT_PAD) act[pos] = (unsigned)k | ((unsigned)c << 16);
    }
  }
  __syncthreads();
  const int na = act_n;
  const bool ok = (na <= ACT_PAD);

  // stage entries: k, c, and up to 3 neighbor ids (absent -> SENT)
  unsigned ae[EPT];
  unsigned short r0[EPT], r1[EPT], r2[EPT];
  int cur[EPT];                  // this thread OWNS these entries' state
#pragma unroll
  for (int e = 0; e < EPT; ++e) {
    unsigned v = act[tid + e * 1024];
    ae[e] = v;
    int k = (int)(v & 0xFFFFu);
    int c = (int)(v >> 16);
    const unsigned short* row = nbr + (size_t)k * K_NBR;
    unsigned w = (c > 0) ? *(const unsigned int*)row : 0u;   // r0 | r1<<16
    r0[e] = (c > 0) ? (unsigned short)(w & 0xFFFFu) : (unsigned short)SENT;
    r1[e] = (c > 1) ? (unsigned short)(w >> 16)     : (unsigned short)SENT;
    r2[e] = (c > 2) ? row[2]                        : (unsigned short)SENT;
    cur[e] = 1;
  }
  __syncthreads();

  if (ok) {
    for (int it = 0; it < 96; ++it) {
      // 15 independent LDS byte reads -> compiler batches/pipelines them
      int m0[EPT], m1[EPT], m2[EPT];
#pragma unroll
      for (int e = 0; e < EPT; ++e) m0[e] = (int)mask[r0[e]];
#pragma unroll
      for (int e = 0; e < EPT; ++e) m1[e] = (int)mask[r1[e]];
#pragma unroll
      for (int e = 0; e < EPT; ++e) m2[e] = (int)mask[r2[e]];
      int any = 0;
#pragma unroll
      for (int e = 0; e < EPT; ++e) {
        unsigned v = ae[e];
        int c = (int)(v >> 16);
        if (!c) continue;
        int kp = (m0[e] ^ 1) & (m1[e] ^ 1) & (m2[e] ^ 1);
        if (c > 3) {   // ~1 point expected: global tail read
          int k = (int)(v & 0xFFFFu);
          const unsigned short* row = nbr + (size_t)k * K_NBR;
          for (int t = 3; t < c; ++t) kp &= (int)mask[row[t]] ^ 1;
        }
        if (kp != cur[e]) {
          cur[e] = kp;
          mask[v & 0xFFFFu] = (unsigned char)kp;   // single writer per entry
          any = 1;
        }
      }
      // count==0 => no writes this sweep => stable state => fixpoint
      if (__syncthreads_count(any) == 0) break;
    }
    // epilogue: active outs straight from registers; inactive written by wscan
    int ks = 0;
#pragma unroll
    for (int e = 0; e < EPT; ++e) {
      unsigned v = ae[e];
      if ((v >> 16) != 0u) {
        out[v & 0xFFFFu] = cur[e];
        ks += cur[e];
      }
    }
#pragma unroll
    for (int off = 32; off > 0; off >>= 1) ks += __shfl_down(ks, off, 64);
    if (lane == 0) atomicAdd(&total, ks);
    __syncthreads();
    if (tid == 0) out[out_size - 1] = (M_PTS - na) + total;
  } else {
    // overflow fallback (statistically never): barriered global sweeps,
    // writes ALL outputs (consistent with wscan's inactive pre-writes).
    __shared__ int changed;
    for (int it = 0; it < 512; ++it) {
      if (tid == 0) changed = 0;
      __syncthreads();
      int any = 0;
      for (int k = tid; k < M_PTS; k += 1024) {
        int c = cnt[k]; if (c > K_NBR) c = K_NBR;
        if (!c) continue;
        int kp = 1;
        for (int t = 0; t < c; ++t) kp &= (int)mask[nbr[k * K_NBR + t]] ^ 1;
        if (kp != (int)mask[k]) { mask[k] = (unsigned char)kp; any = 1; }
      }
      if (any) changed = 1;
      __syncthreads();
      if (!changed) break;
    }
    __syncthreads();
    int ks = 0;
    for (int k = tid; k < M_PTS; k += 1024) {
      int m = (int)mask[k];
      out[k] = m;
      ks += m;
    }
#pragma unroll
    for (int off = 32; off > 0; off >>= 1) ks += __shfl_down(ks, off, 64);
    if (lane == 0) atomicAdd(&total, ks);
    __syncthreads();
    if (tid == 0) out[out_size - 1] = total;
  }
}

extern "C" void kernel_launch(void* const* d_in, const int* in_sizes, int n_in,
                              void* d_out, int out_size, void* d_ws, size_t ws_size,
                              hipStream_t stream) {
  const float* nodes = (const float*)d_in[0];
  const float* score = (const float*)d_in[1];
  int* out = (int*)d_out;

  char* ws = (char*)d_ws;
  float4* pts = (float4*)ws;
  int* cell_cnt = (int*)(ws + 262144);
  int* cnt = (int*)(ws + 327680);
  unsigned short* cell_list = (unsigned short*)(ws + 393216);
  unsigned short* nbr = (unsigned short*)(ws + 770048);

  bin25<<<GRID_N, 1024, 0, stream>>>(nodes, score, pts, cell_cnt, cell_list);
  wscan<<<2048, 256, 0, stream>>>(pts, cell_cnt, cell_list, cnt, nbr, out);
  solve_nb<<<1, 1024, 0, stream>>>(cnt, nbr, out, out_size);
}